// Round 10
// baseline (364.694 us; speedup 1.0000x reference)
//
#include <hip/hip_runtime.h>
#include <hip/hip_bf16.h>

typedef __bf16 bf16x8 __attribute__((ext_vector_type(8)));
typedef float f32x4 __attribute__((ext_vector_type(4)));
typedef unsigned short ushort8v __attribute__((ext_vector_type(8)));
typedef unsigned short ushort4v __attribute__((ext_vector_type(4)));

#define DEV __device__ __forceinline__

DEV unsigned short f2bf(float f) {
    unsigned u = __builtin_bit_cast(unsigned, f);
    unsigned r = (u + 0x7fffu + ((u >> 16) & 1u)) >> 16;
    return (unsigned short)r;
}

DEV float bf2f(unsigned short b) {
    unsigned u = ((unsigned)b) << 16;
    return __builtin_bit_cast(float, u);
}

DEV float wred_sum(float v) {
    #pragma unroll
    for (int o = 32; o > 0; o >>= 1) v += __shfl_xor(v, o, 64);
    return v;
}

// ---------------- fused prep: cvtpad | tr(W1) | tr(W2) | hist, range-dispatched ----------
__global__ __launch_bounds__(256) void prep_k(const float* __restrict__ X,
                                              unsigned short* __restrict__ XO,
                                              const float* __restrict__ W1, unsigned short* __restrict__ W1T,
                                              const float* __restrict__ W2, unsigned short* __restrict__ W2T,
                                              const int* __restrict__ ei, int* __restrict__ count,
                                              int nrows, int E, int Et,
                                              int nbA, int nbB, int nbC) {
    __shared__ unsigned short tile[32][33];
    int bid = blockIdx.x;
    int tid = threadIdx.x;
    if (bid < nbA) {
        int id = bid * 256 + tid;
        int row = id / 96;
        int k0 = (id - row * 96) * 8;
        ushort8v o;
        if (row < nrows) {
            const float* p = X + (size_t)row * 768 + k0;
            float4 a = *(const float4*)p;
            float4 b = *(const float4*)(p + 4);
            o[0] = f2bf(a.x); o[1] = f2bf(a.y); o[2] = f2bf(a.z); o[3] = f2bf(a.w);
            o[4] = f2bf(b.x); o[5] = f2bf(b.y); o[6] = f2bf(b.z); o[7] = f2bf(b.w);
        } else {
            o = (ushort8v)0;
        }
        *(ushort8v*)(XO + (size_t)id * 8) = o;
        return;
    }
    if (bid < nbA + nbB + nbC) {
        const float* W; unsigned short* WT; int K, rel;
        if (bid < nbA + nbB) { W = W1; WT = W1T; K = 768; rel = bid - nbA; }
        else                 { W = W2; WT = W2T; K = 256; rel = bid - nbA - nbB; }
        int kdim = K / 32;
        int kb = (rel % kdim) * 32, fb = (rel / kdim) * 32;
        int c = tid & 31;
        #pragma unroll
        for (int i = 0; i < 4; i++) {
            int r = (tid >> 5) + i * 8;
            tile[r][c] = f2bf(W[(size_t)(kb + r) * 1024 + fb + c]);
        }
        __syncthreads();
        #pragma unroll
        for (int i = 0; i < 4; i++) {
            int r = (tid >> 5) + i * 8;
            WT[(size_t)(fb + r) * K + kb + c] = tile[c][r];
        }
        return;
    }
    int id = (bid - nbA - nbB - nbC) * 256 + tid;
    if (id >= Et) return;
    int dst = (id < E) ? ei[E + id] : (id - E);
    atomicAdd(&count[dst], 1);
}

// ---------------- parallel scan: A (chunk-local) -> B (block sums) -> C (add offsets) ----------
__global__ __launch_bounds__(256) void scanA_k(const int* __restrict__ cnt, int* __restrict__ loc,
                                               int* __restrict__ bsum, int n) {
    __shared__ int ws[4];
    int b = blockIdx.x, tid = threadIdx.x, wave = tid >> 6, lane = tid & 63;
    int gi = b * 256 + tid;
    int v = (gi < n) ? cnt[gi] : 0;
    int s = v;
    #pragma unroll
    for (int o = 1; o < 64; o <<= 1) { int t = __shfl_up(s, o, 64); if (lane >= o) s += t; }
    if (lane == 63) ws[wave] = s;
    __syncthreads();
    int add = 0;
    #pragma unroll
    for (int w = 0; w < 3; w++) if (wave > w) add += ws[w];
    int excl = s - v + add;
    if (gi < n) loc[gi] = excl;
    if (tid == 255) bsum[b] = excl + v;
}

__global__ void scanB_k(int* __restrict__ bsum, int nb) {
    int lane = threadIdx.x;
    int v = (lane < nb) ? bsum[lane] : 0;
    int s = v;
    #pragma unroll
    for (int o = 1; o < 64; o <<= 1) { int t = __shfl_up(s, o, 64); if (lane >= o) s += t; }
    if (lane < nb) bsum[lane] = s - v;   // exclusive
}

__global__ __launch_bounds__(256) void scanC_k(int* __restrict__ indptr, int* __restrict__ cursor,
                                               const int* __restrict__ bsum, int n, int Et) {
    int b = blockIdx.x, gi = b * 256 + threadIdx.x;
    if (gi < n) {
        int v = indptr[gi] + bsum[b];
        indptr[gi] = v;
        cursor[gi] = v;
    }
    if (gi == 0) indptr[n] = Et;
}

__global__ __launch_bounds__(256) void scatter_k(const int* __restrict__ ei, int* __restrict__ cursor,
                                                 int* __restrict__ srcs, int E, int Et) {
    int id = blockIdx.x * 256 + threadIdx.x;
    if (id >= Et) return;
    int s, d;
    if (id < E) { s = ei[id]; d = ei[E + id]; } else { s = id - E; d = s; }
    int pos = atomicAdd(&cursor[d], 1);
    srcs[pos] = s;
}

// ---------------- bf16 GEMM: C[M][1024] = A[M][K] @ BT[1024][K]^T, C output in bf16 ----------
__global__ __launch_bounds__(256) void gemm_k(const unsigned short* __restrict__ A,
                                              const unsigned short* __restrict__ B,
                                              unsigned short* __restrict__ C, int K) {
    __shared__ unsigned short lds_a[128 * 64];
    __shared__ unsigned short lds_b[128 * 64];
    int m0 = blockIdx.x * 128, n0 = blockIdx.y * 128;
    int tid = threadIdx.x, wave = tid >> 6, lane = tid & 63;
    int wr = wave >> 1, wc = wave & 1;
    f32x4 acc[4][4] = {};
    int slotbase = wave * 256;
    for (int kt = 0; kt < K; kt += 64) {
        #pragma unroll
        for (int t = 0; t < 4; t++) {
            int slot = slotbase + t * 64 + lane;
            int row = slot >> 3;
            int cp = slot & 7;
            int cc = cp ^ (row & 7);  // swizzled global source, linear LDS dest
            const unsigned short* ga = A + (size_t)(m0 + row) * K + kt + cc * 8;
            const unsigned short* gb = B + (size_t)(n0 + row) * K + kt + cc * 8;
            __builtin_amdgcn_global_load_lds((const __attribute__((address_space(1))) void*)ga,
                (__attribute__((address_space(3))) void*)(lds_a + (size_t)(slotbase + t * 64) * 8), 16, 0, 0);
            __builtin_amdgcn_global_load_lds((const __attribute__((address_space(1))) void*)gb,
                (__attribute__((address_space(3))) void*)(lds_b + (size_t)(slotbase + t * 64) * 8), 16, 0, 0);
        }
        __syncthreads();
        #pragma unroll
        for (int kk = 0; kk < 2; kk++) {
            bf16x8 af[4], bg[4];
            #pragma unroll
            for (int m = 0; m < 4; m++) {
                int row = wr * 64 + m * 16 + (lane & 15);
                int c = kk * 4 + (lane >> 4);
                int cp = c ^ (row & 7);
                af[m] = *(const bf16x8*)(lds_a + (row * 8 + cp) * 8);
            }
            #pragma unroll
            for (int nn = 0; nn < 4; nn++) {
                int row = wc * 64 + nn * 16 + (lane & 15);
                int c = kk * 4 + (lane >> 4);
                int cp = c ^ (row & 7);
                bg[nn] = *(const bf16x8*)(lds_b + (row * 8 + cp) * 8);
            }
            #pragma unroll
            for (int m = 0; m < 4; m++)
                #pragma unroll
                for (int nn = 0; nn < 4; nn++)
                    acc[m][nn] = __builtin_amdgcn_mfma_f32_16x16x32_bf16(af[m], bg[nn], acc[m][nn], 0, 0, 0);
        }
        __syncthreads();
    }
    // C/D layout: col = lane&15, row = (lane>>4)*4 + reg
    #pragma unroll
    for (int m = 0; m < 4; m++) {
        #pragma unroll
        for (int nn = 0; nn < 4; nn++) {
            int c = n0 + wc * 64 + nn * 16 + (lane & 15);
            #pragma unroll
            for (int j = 0; j < 4; j++) {
                int r = m0 + wr * 64 + m * 16 + (lane >> 4) * 4 + j;
                C[(size_t)r * 1024 + c] = f2bf(acc[m][nn][j]);
            }
        }
    }
}

// ---------------- s/d vectors from bf16 xh ----------
__global__ __launch_bounds__(256) void sd_k(const unsigned short* __restrict__ xh,
                                            const float* __restrict__ asrc, const float* __restrict__ adst,
                                            float* __restrict__ s, float* __restrict__ d) {
    int n = blockIdx.x;
    int tid = threadIdx.x, h = tid >> 6, lane = tid & 63;
    ushort4v u = *(const ushort4v*)(xh + (size_t)n * 1024 + h * 256 + lane * 4);
    float4 va = *(const float4*)(asrc + h * 256 + lane * 4);
    float4 vd = *(const float4*)(adst + h * 256 + lane * 4);
    float x0 = bf2f(u[0]), x1 = bf2f(u[1]), x2 = bf2f(u[2]), x3 = bf2f(u[3]);
    float ps = x0 * va.x + x1 * va.y + x2 * va.z + x3 * va.w;
    float pd = x0 * vd.x + x1 * vd.y + x2 * vd.z + x3 * vd.w;
    ps = wred_sum(ps);
    pd = wred_sum(pd);
    if (lane == 0) { s[n * 4 + h] = ps; d[n * 4 + h] = pd; }
}

// ---------------- attention + aggregation: HEAD-PHASED, two waves per node ----------
// 4 sequential head-phases per block. Phase h gathers ONLY the 512B head-h slice of each
// src row (footprint 5.2MB vs 20.7MB => higher L2 hit). Lane owns 4 ch (8B) of the head
// slice. Persistent acc[4] accumulates (0.25/L_h)*phase_partial. Block barrier per phase
// keeps waves in lockstep; final cross-parity combine in LDS.
__global__ __launch_bounds__(256) void aggr_k(const unsigned short* __restrict__ xh,
                                              const float* __restrict__ svec, const float* __restrict__ dvec,
                                              const int* __restrict__ indptr, const int* __restrict__ srcs,
                                              const float* __restrict__ bias, float* __restrict__ out) {
    __shared__ int   stab[4][64];
    __shared__ float wtab[4][64];
    __shared__ float lpart[4][2][2];    // [phase][nid][parity]
    __shared__ float ob[2][4][64];      // [nid][j][lane]
    int tid = threadIdx.x, wave = tid >> 6, lane = tid & 63;
    int nid = wave >> 1, parity = wave & 1;
    int n = blockIdx.x * 2 + nid;
    int start = indptr[n], end = indptr[n + 1];
    int cnt = end - start;
    int nw = (cnt > parity) ? ((cnt - parity + 1) >> 1) : 0;   // this wave's edge count
    float4 dv4 = ((const float4*)dvec)[n];
    float dhv[4] = {dv4.x, dv4.y, dv4.z, dv4.w};
    const ushort4v* xb4 = (const ushort4v*)xh;   // row = 256 ushort4v units (8B)
    float acc[4] = {0.f, 0.f, 0.f, 0.f};
    #pragma unroll
    for (int h = 0; h < 4; h++) {
        float dh = dhv[h];
        float phacc[4] = {0.f, 0.f, 0.f, 0.f};
        float ls = 0.f;
        for (int c0 = 0; c0 < nw; c0 += 64) {
            int m = min(64, nw - c0);
            if (lane < m) {
                int j = c0 + lane;
                int sv = srcs[start + parity + 2 * j];
                float e = svec[sv * 4 + h] + dh;
                e = e > 0.f ? e : 0.2f * e;
                float wgt = __expf(e);
                ls += wgt;
                stab[wave][lane] = sv;
                wtab[wave][lane] = wgt;
            }
            // same-wave LDS write->read: ordered by lgkmcnt, no barrier needed
            size_t hoff = (size_t)(h * 64 + lane);
            int k = 0;
            for (; k + 8 <= m; k += 8) {
                int s0 = stab[wave][k],     s1 = stab[wave][k + 1];
                int s2 = stab[wave][k + 2], s3 = stab[wave][k + 3];
                int s4 = stab[wave][k + 4], s5 = stab[wave][k + 5];
                int s6 = stab[wave][k + 6], s7 = stab[wave][k + 7];
                float w0 = wtab[wave][k],     w1 = wtab[wave][k + 1];
                float w2 = wtab[wave][k + 2], w3 = wtab[wave][k + 3];
                float w4 = wtab[wave][k + 4], w5 = wtab[wave][k + 5];
                float w6 = wtab[wave][k + 6], w7 = wtab[wave][k + 7];
                ushort4v a0 = xb4[(size_t)s0 * 256 + hoff];
                ushort4v a1 = xb4[(size_t)s1 * 256 + hoff];
                ushort4v a2 = xb4[(size_t)s2 * 256 + hoff];
                ushort4v a3 = xb4[(size_t)s3 * 256 + hoff];
                ushort4v a4 = xb4[(size_t)s4 * 256 + hoff];
                ushort4v a5 = xb4[(size_t)s5 * 256 + hoff];
                ushort4v a6 = xb4[(size_t)s6 * 256 + hoff];
                ushort4v a7 = xb4[(size_t)s7 * 256 + hoff];
                #pragma unroll
                for (int j = 0; j < 4; j++) {
                    phacc[j] += w0 * bf2f(a0[j]) + w1 * bf2f(a1[j])
                              + w2 * bf2f(a2[j]) + w3 * bf2f(a3[j])
                              + w4 * bf2f(a4[j]) + w5 * bf2f(a5[j])
                              + w6 * bf2f(a6[j]) + w7 * bf2f(a7[j]);
                }
            }
            for (; k < m; k++) {
                int s0 = stab[wave][k];
                float w0 = wtab[wave][k];
                ushort4v a0 = xb4[(size_t)s0 * 256 + hoff];
                #pragma unroll
                for (int j = 0; j < 4; j++) phacc[j] += w0 * bf2f(a0[j]);
            }
        }
        ls = wred_sum(ls);
        if (lane == 0) lpart[h][nid][parity] = ls;
        __syncthreads();
        float L = lpart[h][nid][0] + lpart[h][nid][1];
        float sc = 0.25f / L;
        #pragma unroll
        for (int j = 0; j < 4; j++) acc[j] += sc * phacc[j];
    }
    // cross-parity combine
    if (parity == 1) {
        #pragma unroll
        for (int j = 0; j < 4; j++) ob[nid][j][lane] = acc[j];
    }
    __syncthreads();
    if (parity == 0) {
        #pragma unroll
        for (int j = 0; j < 4; j++) acc[j] += ob[nid][j][lane];
        int c0 = lane * 4;
        float4 bv = *(const float4*)(bias + c0);
        float4 ov;
        ov.x = acc[0] + bv.x; ov.y = acc[1] + bv.y;
        ov.z = acc[2] + bv.z; ov.w = acc[3] + bv.w;
        *(float4*)(out + (size_t)n * 256 + c0) = ov;
    }
}

// ---------------- BN stats / apply ----------
__global__ __launch_bounds__(256) void bnstat_k(const float* __restrict__ h, float* __restrict__ bnsum,
                                                float* __restrict__ bnss, int n, int rpb) {
    int c = threadIdx.x;
    int r0 = blockIdx.x * rpb;
    int r1 = min(r0 + rpb, n);
    float s = 0.f, q = 0.f;
    for (int r = r0; r < r1; r++) {
        float v = h[(size_t)r * 256 + c];
        s += v; q += v * v;
    }
    atomicAdd(&bnsum[c], s);
    atomicAdd(&bnss[c], q);
}

__global__ __launch_bounds__(256) void bnapply_k(const float* __restrict__ h, const float* __restrict__ bnsum,
                                                 const float* __restrict__ bnss, const float* __restrict__ gamma,
                                                 const float* __restrict__ beta, unsigned short* __restrict__ o,
                                                 int nrows, float invn) {
    int row = blockIdx.x, c = threadIdx.x;
    unsigned short r;
    if (row < nrows) {
        float mu = bnsum[c] * invn;
        float var = bnss[c] * invn - mu * mu;
        float v = (h[(size_t)row * 256 + c] - mu) * rsqrtf(var + 1e-5f) * gamma[c] + beta[c];
        v = fmaxf(v, 0.f);
        r = f2bf(v);
    } else {
        r = 0;
    }
    o[(size_t)row * 256 + c] = r;
}

extern "C" void kernel_launch(void* const* d_in, const int* in_sizes, int n_in,
                              void* d_out, int out_size, void* d_ws, size_t ws_size,
                              hipStream_t stream) {
    const float* x     = (const float*)d_in[0];
    const int*   ei    = (const int*)d_in[1];
    const float* W1    = (const float*)d_in[2];
    const float* as1   = (const float*)d_in[3];
    const float* ad1   = (const float*)d_in[4];
    const float* b1    = (const float*)d_in[5];
    const float* gamma = (const float*)d_in[6];
    const float* beta  = (const float*)d_in[7];
    const float* W2    = (const float*)d_in[8];
    const float* as2   = (const float*)d_in[9];
    const float* ad2   = (const float*)d_in[10];
    const float* b2    = (const float*)d_in[11];
    float* out = (float*)d_out;

    const int N = in_sizes[0] / 768;     // 10000 (multiple of 2)
    const int E = in_sizes[1] / 2;       // 160000
    const int Et = E + N;                // edges + self loops
    const int Mpad = ((N + 127) / 128) * 128;  // 10112

    char* w = (char*)d_ws;
    size_t o = 0;
    auto alloc = [&](size_t b) { size_t r = o; o += (b + 255) & ~(size_t)255; return r; };
    unsigned short* xh     = (unsigned short*)(w + alloc((size_t)Mpad * 1024 * 2));
    unsigned short* xbf    = (unsigned short*)(w + alloc((size_t)Mpad * 768 * 2));
    unsigned short* hbf    = (unsigned short*)(w + alloc((size_t)Mpad * 256 * 2));
    unsigned short* w1t    = (unsigned short*)(w + alloc((size_t)1024 * 768 * 2));
    unsigned short* w2t    = (unsigned short*)(w + alloc((size_t)1024 * 256 * 2));
    float*          svec   = (float*)(w + alloc((size_t)N * 4 * 4));
    float*          dvec   = (float*)(w + alloc((size_t)N * 4 * 4));
    float*          hbuf   = (float*)(w + alloc((size_t)N * 256 * 4));
    int*            indptr = (int*)(w + alloc((size_t)(N + 1) * 4));
    int*            cursor = (int*)(w + alloc((size_t)N * 4));
    int*            count  = (int*)(w + alloc((size_t)N * 4));
    int*            bsum   = (int*)(w + alloc(256));
    float*          bnsum  = (float*)(w + alloc(256 * 4));   // bnss directly after: one memset covers both
    float*          bnss   = (float*)(w + alloc(256 * 4));
    int*            srcs   = (int*)(w + alloc((size_t)Et * 4));

    hipMemsetAsync(count, 0, (size_t)N * 4, stream);
    hipMemsetAsync(bnsum, 0, 2048, stream);  // bnsum + bnss (contiguous, 256-aligned)

    // fused prep: cvtpad | tr(W1) | tr(W2) | hist
    int nbA = (Mpad * 96) / 256;         // 3792
    int nbB = (768 / 32) * (1024 / 32);  // 768
    int nbC = (256 / 32) * (1024 / 32);  // 256
    int nbD = (Et + 255) / 256;          // 665
    prep_k<<<nbA + nbB + nbC + nbD, 256, 0, stream>>>(x, xbf, W1, w1t, W2, w2t, ei, count,
                                                      N, E, Et, nbA, nbB, nbC);
    int nbS = (N + 255) / 256;           // 40
    scanA_k<<<nbS, 256, 0, stream>>>(count, indptr, bsum, N);
    scanB_k<<<1, 64, 0, stream>>>(bsum, nbS);
    scanC_k<<<nbS, 256, 0, stream>>>(indptr, cursor, bsum, N, Et);
    scatter_k<<<(Et + 255) / 256, 256, 0, stream>>>(ei, cursor, srcs, E, Et);

    // layer 1
    gemm_k<<<dim3(Mpad / 128, 8), 256, 0, stream>>>(xbf, w1t, xh, 768);
    sd_k<<<N, 256, 0, stream>>>(xh, as1, ad1, svec, dvec);
    aggr_k<<<N / 2, 256, 0, stream>>>(xh, svec, dvec, indptr, srcs, b1, hbuf);

    // BN + ReLU -> bf16 padded
    bnstat_k<<<80, 256, 0, stream>>>(hbuf, bnsum, bnss, N, (N + 79) / 80);
    bnapply_k<<<Mpad, 256, 0, stream>>>(hbuf, bnsum, bnss, gamma, beta, hbf, N, 1.0f / (float)N);

    // layer 2
    gemm_k<<<dim3(Mpad / 128, 8), 256, 0, stream>>>(hbf, w2t, xh, 256);
    sd_k<<<N, 256, 0, stream>>>(xh, as2, ad2, svec, dvec);
    aggr_k<<<N / 2, 256, 0, stream>>>(xh, svec, dvec, indptr, srcs, b2, out);
}

// Round 12
// 339.672 us; speedup vs baseline: 1.0737x; 1.0737x over previous
//
#include <hip/hip_runtime.h>
#include <hip/hip_bf16.h>

typedef __bf16 bf16x8 __attribute__((ext_vector_type(8)));
typedef float f32x4 __attribute__((ext_vector_type(4)));
typedef unsigned short ushort8v __attribute__((ext_vector_type(8)));
typedef unsigned short ushort4v __attribute__((ext_vector_type(4)));

#define DEV __device__ __forceinline__

DEV unsigned short f2bf(float f) {
    unsigned u = __builtin_bit_cast(unsigned, f);
    unsigned r = (u + 0x7fffu + ((u >> 16) & 1u)) >> 16;
    return (unsigned short)r;
}

DEV float bf2f(unsigned short b) {
    unsigned u = ((unsigned)b) << 16;
    return __builtin_bit_cast(float, u);
}

DEV float wred_sum(float v) {
    #pragma unroll
    for (int o = 32; o > 0; o >>= 1) v += __shfl_xor(v, o, 64);
    return v;
}

// ---------------- fused prep: cvtpad | tr(W1) | tr(W2) | hist, range-dispatched ----------
__global__ __launch_bounds__(256) void prep_k(const float* __restrict__ X,
                                              unsigned short* __restrict__ XO,
                                              const float* __restrict__ W1, unsigned short* __restrict__ W1T,
                                              const float* __restrict__ W2, unsigned short* __restrict__ W2T,
                                              const int* __restrict__ ei, int* __restrict__ count,
                                              int nrows, int E, int Et,
                                              int nbA, int nbB, int nbC) {
    __shared__ unsigned short tile[32][33];
    int bid = blockIdx.x;
    int tid = threadIdx.x;
    if (bid < nbA) {
        int id = bid * 256 + tid;
        int row = id / 96;
        int k0 = (id - row * 96) * 8;
        ushort8v o;
        if (row < nrows) {
            const float* p = X + (size_t)row * 768 + k0;
            float4 a = *(const float4*)p;
            float4 b = *(const float4*)(p + 4);
            o[0] = f2bf(a.x); o[1] = f2bf(a.y); o[2] = f2bf(a.z); o[3] = f2bf(a.w);
            o[4] = f2bf(b.x); o[5] = f2bf(b.y); o[6] = f2bf(b.z); o[7] = f2bf(b.w);
        } else {
            o = (ushort8v)0;
        }
        *(ushort8v*)(XO + (size_t)id * 8) = o;
        return;
    }
    if (bid < nbA + nbB + nbC) {
        const float* W; unsigned short* WT; int K, rel;
        if (bid < nbA + nbB) { W = W1; WT = W1T; K = 768; rel = bid - nbA; }
        else                 { W = W2; WT = W2T; K = 256; rel = bid - nbA - nbB; }
        int kdim = K / 32;
        int kb = (rel % kdim) * 32, fb = (rel / kdim) * 32;
        int c = tid & 31;
        #pragma unroll
        for (int i = 0; i < 4; i++) {
            int r = (tid >> 5) + i * 8;
            tile[r][c] = f2bf(W[(size_t)(kb + r) * 1024 + fb + c]);
        }
        __syncthreads();
        #pragma unroll
        for (int i = 0; i < 4; i++) {
            int r = (tid >> 5) + i * 8;
            WT[(size_t)(fb + r) * K + kb + c] = tile[c][r];
        }
        return;
    }
    int id = (bid - nbA - nbB - nbC) * 256 + tid;
    if (id >= Et) return;
    int dst = (id < E) ? ei[E + id] : (id - E);
    atomicAdd(&count[dst], 1);
}

// ---------------- parallel scan: A (chunk-local) -> C (adds redundantly-scanned block offsets) --
__global__ __launch_bounds__(256) void scanA_k(const int* __restrict__ cnt, int* __restrict__ loc,
                                               int* __restrict__ bsum, int n) {
    __shared__ int ws[4];
    int b = blockIdx.x, tid = threadIdx.x, wave = tid >> 6, lane = tid & 63;
    int gi = b * 256 + tid;
    int v = (gi < n) ? cnt[gi] : 0;
    int s = v;
    #pragma unroll
    for (int o = 1; o < 64; o <<= 1) { int t = __shfl_up(s, o, 64); if (lane >= o) s += t; }
    if (lane == 63) ws[wave] = s;
    __syncthreads();
    int add = 0;
    #pragma unroll
    for (int w = 0; w < 3; w++) if (wave > w) add += ws[w];
    int excl = s - v + add;
    if (gi < n) loc[gi] = excl;
    if (tid == 255) bsum[b] = excl + v;
}

// each block redundantly sums bsum[0..b-1] (nb<=64) - removes the scanB launch
__global__ __launch_bounds__(256) void scanC_k(int* __restrict__ indptr, int* __restrict__ cursor,
                                               const int* __restrict__ bsum, int n, int Et, int nb) {
    __shared__ int boff_s;
    int b = blockIdx.x, tid = threadIdx.x;
    if (tid < 64) {
        int lane = tid;
        int v = (lane < nb && lane < b) ? bsum[lane] : 0;
        #pragma unroll
        for (int o = 32; o > 0; o >>= 1) v += __shfl_xor(v, o, 64);
        if (lane == 0) boff_s = v;
    }
    __syncthreads();
    int boff = boff_s;
    int gi = b * 256 + tid;
    if (gi < n) {
        int v = indptr[gi] + boff;
        indptr[gi] = v;
        cursor[gi] = v;
    }
    if (gi == 0) indptr[n] = Et;
}

__global__ __launch_bounds__(256) void scatter_k(const int* __restrict__ ei, int* __restrict__ cursor,
                                                 int* __restrict__ srcs, int E, int Et) {
    int id = blockIdx.x * 256 + threadIdx.x;
    if (id >= Et) return;
    int s, d;
    if (id < E) { s = ei[id]; d = ei[E + id]; } else { s = id - E; d = s; }
    int pos = atomicAdd(&cursor[d], 1);
    srcs[pos] = s;
}

// ---------------- bf16 GEMM + fused s/d partials ----------
// C[M][1024] = A[M][K] @ BT[1024][K]^T, C in bf16. Column tile (128-wide, 128-aligned) lies
// within ONE head (head = n0>>8), so each wave computes per-row partial dots with a_src/a_dst
// over its 64 columns, reduces across the 16-lane column group, atomicAdds into sv/dv.
__global__ __launch_bounds__(256) void gemm_k(const unsigned short* __restrict__ A,
                                              const unsigned short* __restrict__ B,
                                              unsigned short* __restrict__ C, int K,
                                              const float* __restrict__ asrc,
                                              const float* __restrict__ adst,
                                              float* __restrict__ sv, float* __restrict__ dv,
                                              int nN) {
    __shared__ unsigned short lds_a[128 * 64];
    __shared__ unsigned short lds_b[128 * 64];
    int m0 = blockIdx.x * 128, n0 = blockIdx.y * 128;
    int tid = threadIdx.x, wave = tid >> 6, lane = tid & 63;
    int wr = wave >> 1, wc = wave & 1;
    f32x4 acc[4][4] = {};
    int slotbase = wave * 256;
    for (int kt = 0; kt < K; kt += 64) {
        #pragma unroll
        for (int t = 0; t < 4; t++) {
            int slot = slotbase + t * 64 + lane;
            int row = slot >> 3;
            int cp = slot & 7;
            int cc = cp ^ (row & 7);  // swizzled global source, linear LDS dest
            const unsigned short* ga = A + (size_t)(m0 + row) * K + kt + cc * 8;
            const unsigned short* gb = B + (size_t)(n0 + row) * K + kt + cc * 8;
            __builtin_amdgcn_global_load_lds((const __attribute__((address_space(1))) void*)ga,
                (__attribute__((address_space(3))) void*)(lds_a + (size_t)(slotbase + t * 64) * 8), 16, 0, 0);
            __builtin_amdgcn_global_load_lds((const __attribute__((address_space(1))) void*)gb,
                (__attribute__((address_space(3))) void*)(lds_b + (size_t)(slotbase + t * 64) * 8), 16, 0, 0);
        }
        __syncthreads();
        #pragma unroll
        for (int kk = 0; kk < 2; kk++) {
            bf16x8 af[4], bg[4];
            #pragma unroll
            for (int m = 0; m < 4; m++) {
                int row = wr * 64 + m * 16 + (lane & 15);
                int c = kk * 4 + (lane >> 4);
                int cp = c ^ (row & 7);
                af[m] = *(const bf16x8*)(lds_a + (row * 8 + cp) * 8);
            }
            #pragma unroll
            for (int nn = 0; nn < 4; nn++) {
                int row = wc * 64 + nn * 16 + (lane & 15);
                int c = kk * 4 + (lane >> 4);
                int cp = c ^ (row & 7);
                bg[nn] = *(const bf16x8*)(lds_b + (row * 8 + cp) * 8);
            }
            #pragma unroll
            for (int m = 0; m < 4; m++)
                #pragma unroll
                for (int nn = 0; nn < 4; nn++)
                    acc[m][nn] = __builtin_amdgcn_mfma_f32_16x16x32_bf16(af[m], bg[nn], acc[m][nn], 0, 0, 0);
        }
        __syncthreads();
    }
    // C/D layout: col = lane&15, row = (lane>>4)*4 + reg
    #pragma unroll
    for (int m = 0; m < 4; m++) {
        #pragma unroll
        for (int nn = 0; nn < 4; nn++) {
            int c = n0 + wc * 64 + nn * 16 + (lane & 15);
            #pragma unroll
            for (int j = 0; j < 4; j++) {
                int r = m0 + wr * 64 + m * 16 + (lane >> 4) * 4 + j;
                C[(size_t)r * 1024 + c] = f2bf(acc[m][nn][j]);
            }
        }
    }
    // fused s/d partials
    int headc = n0 >> 8;
    float asv[4], adv[4];
    #pragma unroll
    for (int nn = 0; nn < 4; nn++) {
        int c = n0 + wc * 64 + nn * 16 + (lane & 15);
        asv[nn] = asrc[c];
        adv[nn] = adst[c];
    }
    #pragma unroll
    for (int m = 0; m < 4; m++) {
        #pragma unroll
        for (int j = 0; j < 4; j++) {
            float ps = 0.f, pd = 0.f;
            #pragma unroll
            for (int nn = 0; nn < 4; nn++) {
                ps += acc[m][nn][j] * asv[nn];
                pd += acc[m][nn][j] * adv[nn];
            }
            #pragma unroll
            for (int o2 = 1; o2 < 16; o2 <<= 1) {
                ps += __shfl_xor(ps, o2, 64);
                pd += __shfl_xor(pd, o2, 64);
            }
            if ((lane & 15) == 0) {
                int r = m0 + wr * 64 + m * 16 + (lane >> 4) * 4 + j;
                if (r < nN) {
                    atomicAdd(&sv[r * 4 + headc], ps);
                    atomicAdd(&dv[r * 4 + headc], pd);
                }
            }
        }
    }
}

// ---------------- attention + aggregation: TWO WAVES PER NODE, prefetched edge metadata ----------
// Max-free softmax. Per 64-edge chunk: lane l coalesced-loads its edge's src index + svec float4,
// computes all 4 head weights, deposits into per-wave LDS tables (wave-synchronous, no barrier).
// Gather loop is then dependency-free: broadcast LDS reads + 8 independent 16B loads per 4 edges.
// L accumulated per-lane in registers, reduced once at the end.
__global__ __launch_bounds__(256) void aggr_k(const unsigned short* __restrict__ xh,
                                              const float* __restrict__ svec, const float* __restrict__ dvec,
                                              const int* __restrict__ indptr, const int* __restrict__ srcs,
                                              const float* __restrict__ bias, float* __restrict__ out) {
    __shared__ float ob[2][16][64];     // [nid][acc j][lane] - lane-major, conflict-free
    __shared__ float lpart[2][4];
    __shared__ int   stab[4][64];
    __shared__ float wtab[4][64][4];
    int tid = threadIdx.x, wave = tid >> 6, lane = tid & 63;
    int nid = wave >> 1, parity = wave & 1;
    int n = blockIdx.x * 2 + nid;
    int head = lane >> 4;
    int start = indptr[n], end = indptr[n + 1];
    int cnt = end - start;
    float4 dv4 = ((const float4*)dvec)[n];
    const ushort8v* xb = (const ushort8v*)xh;   // row = 128 ushort8v
    size_t loff = (size_t)(lane << 1);
    float acc[16];
    #pragma unroll
    for (int j = 0; j < 16; j++) acc[j] = 0.f;
    float ls0 = 0.f, ls1 = 0.f, ls2 = 0.f, ls3 = 0.f;
    int nw = (cnt > parity) ? ((cnt - parity + 1) >> 1) : 0;   // this wave's edge count
    for (int c0 = 0; c0 < nw; c0 += 64) {
        int m = min(64, nw - c0);
        if (lane < m) {
            int j = c0 + lane;
            int sv = srcs[start + parity + 2 * j];
            float4 s4 = ((const float4*)svec)[sv];
            float e0 = s4.x + dv4.x, e1 = s4.y + dv4.y, e2 = s4.z + dv4.z, e3 = s4.w + dv4.w;
            e0 = e0 > 0.f ? e0 : 0.2f * e0; e1 = e1 > 0.f ? e1 : 0.2f * e1;
            e2 = e2 > 0.f ? e2 : 0.2f * e2; e3 = e3 > 0.f ? e3 : 0.2f * e3;
            float w0 = __expf(e0), w1 = __expf(e1), w2 = __expf(e2), w3 = __expf(e3);
            ls0 += w0; ls1 += w1; ls2 += w2; ls3 += w3;
            stab[wave][lane] = sv;
            float4 wv = {w0, w1, w2, w3};
            *(float4*)&wtab[wave][lane][0] = wv;
        }
        // same-wave LDS write->read: ordered by lgkmcnt, no barrier needed
        int k = 0;
        for (; k + 4 <= m; k += 4) {
            int s0 = stab[wave][k], s1 = stab[wave][k + 1];
            int s2 = stab[wave][k + 2], s3 = stab[wave][k + 3];
            float w0 = wtab[wave][k][head],     w1 = wtab[wave][k + 1][head];
            float w2 = wtab[wave][k + 2][head], w3 = wtab[wave][k + 3][head];
            ushort8v a0 = xb[(size_t)s0 * 128 + loff], a1 = xb[(size_t)s0 * 128 + loff + 1];
            ushort8v b0 = xb[(size_t)s1 * 128 + loff], b1 = xb[(size_t)s1 * 128 + loff + 1];
            ushort8v c0v = xb[(size_t)s2 * 128 + loff], c1v = xb[(size_t)s2 * 128 + loff + 1];
            ushort8v d0 = xb[(size_t)s3 * 128 + loff], d1 = xb[(size_t)s3 * 128 + loff + 1];
            #pragma unroll
            for (int j = 0; j < 8; j++) {
                acc[j]     += w0 * bf2f(a0[j]) + w1 * bf2f(b0[j]) + w2 * bf2f(c0v[j]) + w3 * bf2f(d0[j]);
                acc[8 + j] += w0 * bf2f(a1[j]) + w1 * bf2f(b1[j]) + w2 * bf2f(c1v[j]) + w3 * bf2f(d1[j]);
            }
        }
        for (; k < m; k++) {
            int s0 = stab[wave][k];
            float w0 = wtab[wave][k][head];
            ushort8v a0 = xb[(size_t)s0 * 128 + loff], a1 = xb[(size_t)s0 * 128 + loff + 1];
            #pragma unroll
            for (int j = 0; j < 8; j++) {
                acc[j]     += w0 * bf2f(a0[j]);
                acc[8 + j] += w0 * bf2f(a1[j]);
            }
        }
    }
    ls0 = wred_sum(ls0); ls1 = wred_sum(ls1); ls2 = wred_sum(ls2); ls3 = wred_sum(ls3);
    if (parity == 1) {
        #pragma unroll
        for (int j = 0; j < 16; j++) ob[nid][j][lane] = acc[j];
        if (lane == 0) {
            lpart[nid][0] = ls0; lpart[nid][1] = ls1;
            lpart[nid][2] = ls2; lpart[nid][3] = ls3;
        }
    }
    __syncthreads();
    if (parity == 0) {
        #pragma unroll
        for (int j = 0; j < 16; j++) acc[j] += ob[nid][j][lane];
        float Lown = head < 2 ? (head == 0 ? ls0 : ls1) : (head == 2 ? ls2 : ls3);
        float L = Lown + lpart[nid][head];
        float inv = 0.25f / L;   // fold head-mean
        #pragma unroll
        for (int j = 0; j < 16; j++) {
            float r = acc[j] * inv;
            r += __shfl_xor(r, 16, 64);
            r += __shfl_xor(r, 32, 64);
            acc[j] = r;
        }
        if (lane < 16) {
            int c0 = lane << 4;
            const float4* bp = (const float4*)(bias + c0);
            float* op = out + (size_t)n * 256 + c0;
            #pragma unroll
            for (int q = 0; q < 4; q++) {
                float4 bv = bp[q];
                float4 ov;
                ov.x = acc[q * 4 + 0] + bv.x;
                ov.y = acc[q * 4 + 1] + bv.y;
                ov.z = acc[q * 4 + 2] + bv.z;
                ov.w = acc[q * 4 + 3] + bv.w;
                *(float4*)(op + q * 4) = ov;
            }
        }
    }
}

// ---------------- BN stats / apply ----------
__global__ __launch_bounds__(256) void bnstat_k(const float* __restrict__ h, float* __restrict__ bnsum,
                                                float* __restrict__ bnss, int n, int rpb) {
    int c = threadIdx.x;
    int r0 = blockIdx.x * rpb;
    int r1 = min(r0 + rpb, n);
    float s = 0.f, q = 0.f;
    for (int r = r0; r < r1; r++) {
        float v = h[(size_t)r * 256 + c];
        s += v; q += v * v;
    }
    atomicAdd(&bnsum[c], s);
    atomicAdd(&bnss[c], q);
}

__global__ __launch_bounds__(256) void bnapply_k(const float* __restrict__ h, const float* __restrict__ bnsum,
                                                 const float* __restrict__ bnss, const float* __restrict__ gamma,
                                                 const float* __restrict__ beta, unsigned short* __restrict__ o,
                                                 int nrows, float invn) {
    int row = blockIdx.x, c = threadIdx.x;
    unsigned short r;
    if (row < nrows) {
        float mu = bnsum[c] * invn;
        float var = bnss[c] * invn - mu * mu;
        float v = (h[(size_t)row * 256 + c] - mu) * rsqrtf(var + 1e-5f) * gamma[c] + beta[c];
        v = fmaxf(v, 0.f);
        r = f2bf(v);
    } else {
        r = 0;
    }
    o[(size_t)row * 256 + c] = r;
}

extern "C" void kernel_launch(void* const* d_in, const int* in_sizes, int n_in,
                              void* d_out, int out_size, void* d_ws, size_t ws_size,
                              hipStream_t stream) {
    const float* x     = (const float*)d_in[0];
    const int*   ei    = (const int*)d_in[1];
    const float* W1    = (const float*)d_in[2];
    const float* as1   = (const float*)d_in[3];
    const float* ad1   = (const float*)d_in[4];
    const float* b1    = (const float*)d_in[5];
    const float* gamma = (const float*)d_in[6];
    const float* beta  = (const float*)d_in[7];
    const float* W2    = (const float*)d_in[8];
    const float* as2   = (const float*)d_in[9];
    const float* ad2   = (const float*)d_in[10];
    const float* b2    = (const float*)d_in[11];
    float* out = (float*)d_out;

    const int N = in_sizes[0] / 768;     // 10000 (multiple of 2)
    const int E = in_sizes[1] / 2;       // 160000
    const int Et = E + N;                // edges + self loops
    const int Mpad = ((N + 127) / 128) * 128;  // 10112

    char* w = (char*)d_ws;
    size_t o = 0;
    auto alloc = [&](size_t b) { size_t r = o; o += (b + 255) & ~(size_t)255; return r; };
    unsigned short* xh     = (unsigned short*)(w + alloc((size_t)Mpad * 1024 * 2));
    unsigned short* xbf    = (unsigned short*)(w + alloc((size_t)Mpad * 768 * 2));
    unsigned short* hbf    = (unsigned short*)(w + alloc((size_t)Mpad * 256 * 2));
    unsigned short* w1t    = (unsigned short*)(w + alloc((size_t)1024 * 768 * 2));
    unsigned short* w2t    = (unsigned short*)(w + alloc((size_t)1024 * 256 * 2));
    size_t svoff = alloc((size_t)N * 4 * 4);          // svec
    float*          svec   = (float*)(w + svoff);
    size_t dvoff = alloc((size_t)N * 4 * 4);          // dvec (adjacent)
    float*          dvec   = (float*)(w + dvoff);
    size_t sdbytes = dvoff + (size_t)N * 16 - svoff;  // covers svec+dvec
    float*          hbuf   = (float*)(w + alloc((size_t)N * 256 * 4));
    int*            indptr = (int*)(w + alloc((size_t)(N + 1) * 4));
    int*            cursor = (int*)(w + alloc((size_t)N * 4));
    int*            count  = (int*)(w + alloc((size_t)N * 4));
    int*            bsum   = (int*)(w + alloc(256));
    float*          bnsum  = (float*)(w + alloc(256 * 4));   // bnss directly after: one memset covers both
    float*          bnss   = (float*)(w + alloc(256 * 4));
    int*            srcs   = (int*)(w + alloc((size_t)Et * 4));

    hipMemsetAsync(count, 0, (size_t)N * 4, stream);
    hipMemsetAsync(bnsum, 0, 2048, stream);        // bnsum + bnss (contiguous, 256-aligned)
    hipMemsetAsync(svec, 0, sdbytes, stream);      // svec + dvec for layer 1

    // fused prep: cvtpad | tr(W1) | tr(W2) | hist
    int nbA = (Mpad * 96) / 256;         // 3792
    int nbB = (768 / 32) * (1024 / 32);  // 768
    int nbC = (256 / 32) * (1024 / 32);  // 256
    int nbD = (Et + 255) / 256;          // 665
    prep_k<<<nbA + nbB + nbC + nbD, 256, 0, stream>>>(x, xbf, W1, w1t, W2, w2t, ei, count,
                                                      N, E, Et, nbA, nbB, nbC);
    int nbS = (N + 255) / 256;           // 40
    scanA_k<<<nbS, 256, 0, stream>>>(count, indptr, bsum, N);
    scanC_k<<<nbS, 256, 0, stream>>>(indptr, cursor, bsum, N, Et, nbS);
    scatter_k<<<(Et + 255) / 256, 256, 0, stream>>>(ei, cursor, srcs, E, Et);

    // layer 1 (gemm computes svec/dvec in its epilogue)
    gemm_k<<<dim3(Mpad / 128, 8), 256, 0, stream>>>(xbf, w1t, xh, 768, as1, ad1, svec, dvec, N);
    aggr_k<<<N / 2, 256, 0, stream>>>(xh, svec, dvec, indptr, srcs, b1, hbuf);

    // BN + ReLU -> bf16 padded
    bnstat_k<<<80, 256, 0, stream>>>(hbuf, bnsum, bnss, N, (N + 79) / 80);
    bnapply_k<<<Mpad, 256, 0, stream>>>(hbuf, bnsum, bnss, gamma, beta, hbf, N, 1.0f / (float)N);

    // layer 2
    hipMemsetAsync(svec, 0, sdbytes, stream);      // re-zero svec + dvec for layer 2
    gemm_k<<<dim3(Mpad / 128, 8), 256, 0, stream>>>(hbf, w2t, xh, 256, as2, ad2, svec, dvec, N);
    aggr_k<<<N / 2, 256, 0, stream>>>(xh, svec, dvec, indptr, srcs, b2, out);
}

// Round 13
// 291.371 us; speedup vs baseline: 1.2516x; 1.1658x over previous
//
#include <hip/hip_runtime.h>
#include <hip/hip_bf16.h>

typedef __bf16 bf16x8 __attribute__((ext_vector_type(8)));
typedef float f32x4 __attribute__((ext_vector_type(4)));
typedef unsigned short ushort8v __attribute__((ext_vector_type(8)));
typedef unsigned short ushort4v __attribute__((ext_vector_type(4)));

#define DEV __device__ __forceinline__

DEV unsigned short f2bf(float f) {
    unsigned u = __builtin_bit_cast(unsigned, f);
    unsigned r = (u + 0x7fffu + ((u >> 16) & 1u)) >> 16;
    return (unsigned short)r;
}

DEV float bf2f(unsigned short b) {
    unsigned u = ((unsigned)b) << 16;
    return __builtin_bit_cast(float, u);
}

DEV float wred_sum(float v) {
    #pragma unroll
    for (int o = 32; o > 0; o >>= 1) v += __shfl_xor(v, o, 64);
    return v;
}

// ---------------- fused prep: cvtpad | tr(W1) | tr(W2) | hist, range-dispatched ----------
__global__ __launch_bounds__(256) void prep_k(const float* __restrict__ X,
                                              unsigned short* __restrict__ XO,
                                              const float* __restrict__ W1, unsigned short* __restrict__ W1T,
                                              const float* __restrict__ W2, unsigned short* __restrict__ W2T,
                                              const int* __restrict__ ei, int* __restrict__ count,
                                              int nrows, int E, int Et,
                                              int nbA, int nbB, int nbC) {
    __shared__ unsigned short tile[32][33];
    int bid = blockIdx.x;
    int tid = threadIdx.x;
    if (bid < nbA) {
        int id = bid * 256 + tid;
        int row = id / 96;
        int k0 = (id - row * 96) * 8;
        ushort8v o;
        if (row < nrows) {
            const float* p = X + (size_t)row * 768 + k0;
            float4 a = *(const float4*)p;
            float4 b = *(const float4*)(p + 4);
            o[0] = f2bf(a.x); o[1] = f2bf(a.y); o[2] = f2bf(a.z); o[3] = f2bf(a.w);
            o[4] = f2bf(b.x); o[5] = f2bf(b.y); o[6] = f2bf(b.z); o[7] = f2bf(b.w);
        } else {
            o = (ushort8v)0;
        }
        *(ushort8v*)(XO + (size_t)id * 8) = o;
        return;
    }
    if (bid < nbA + nbB + nbC) {
        const float* W; unsigned short* WT; int K, rel;
        if (bid < nbA + nbB) { W = W1; WT = W1T; K = 768; rel = bid - nbA; }
        else                 { W = W2; WT = W2T; K = 256; rel = bid - nbA - nbB; }
        int kdim = K / 32;
        int kb = (rel % kdim) * 32, fb = (rel / kdim) * 32;
        int c = tid & 31;
        #pragma unroll
        for (int i = 0; i < 4; i++) {
            int r = (tid >> 5) + i * 8;
            tile[r][c] = f2bf(W[(size_t)(kb + r) * 1024 + fb + c]);
        }
        __syncthreads();
        #pragma unroll
        for (int i = 0; i < 4; i++) {
            int r = (tid >> 5) + i * 8;
            WT[(size_t)(fb + r) * K + kb + c] = tile[c][r];
        }
        return;
    }
    int id = (bid - nbA - nbB - nbC) * 256 + tid;
    if (id >= Et) return;
    int dst = (id < E) ? ei[E + id] : (id - E);
    atomicAdd(&count[dst], 1);
}

// ---------------- parallel scan: A (chunk-local) -> C (adds redundantly-scanned block offsets) --
__global__ __launch_bounds__(256) void scanA_k(const int* __restrict__ cnt, int* __restrict__ loc,
                                               int* __restrict__ bsum, int n) {
    __shared__ int ws[4];
    int b = blockIdx.x, tid = threadIdx.x, wave = tid >> 6, lane = tid & 63;
    int gi = b * 256 + tid;
    int v = (gi < n) ? cnt[gi] : 0;
    int s = v;
    #pragma unroll
    for (int o = 1; o < 64; o <<= 1) { int t = __shfl_up(s, o, 64); if (lane >= o) s += t; }
    if (lane == 63) ws[wave] = s;
    __syncthreads();
    int add = 0;
    #pragma unroll
    for (int w = 0; w < 3; w++) if (wave > w) add += ws[w];
    int excl = s - v + add;
    if (gi < n) loc[gi] = excl;
    if (tid == 255) bsum[b] = excl + v;
}

// each block redundantly sums bsum[0..b-1] (nb<=64) - removes the scanB launch
__global__ __launch_bounds__(256) void scanC_k(int* __restrict__ indptr, int* __restrict__ cursor,
                                               const int* __restrict__ bsum, int n, int Et, int nb) {
    __shared__ int boff_s;
    int b = blockIdx.x, tid = threadIdx.x;
    if (tid < 64) {
        int lane = tid;
        int v = (lane < nb && lane < b) ? bsum[lane] : 0;
        #pragma unroll
        for (int o = 32; o > 0; o >>= 1) v += __shfl_xor(v, o, 64);
        if (lane == 0) boff_s = v;
    }
    __syncthreads();
    int boff = boff_s;
    int gi = b * 256 + tid;
    if (gi < n) {
        int v = indptr[gi] + boff;
        indptr[gi] = v;
        cursor[gi] = v;
    }
    if (gi == 0) indptr[n] = Et;
}

__global__ __launch_bounds__(256) void scatter_k(const int* __restrict__ ei, int* __restrict__ cursor,
                                                 int* __restrict__ srcs, int E, int Et) {
    int id = blockIdx.x * 256 + threadIdx.x;
    if (id >= Et) return;
    int s, d;
    if (id < E) { s = ei[id]; d = ei[E + id]; } else { s = id - E; d = s; }
    int pos = atomicAdd(&cursor[d], 1);
    srcs[pos] = s;
}

// ---------------- bf16 GEMM: 64x128 tile for grid occupancy ----------
// C[M][1024] = A[M][K] @ BT[1024][K]^T, C in bf16. grid = (M/64, 8), 1256 blocks.
// 4 waves, each computes 64x32 (4 m-frags x 2 n-frags). LDS 24KB -> 6 blocks/CU.
__global__ __launch_bounds__(256) void gemm_k(const unsigned short* __restrict__ A,
                                              const unsigned short* __restrict__ B,
                                              unsigned short* __restrict__ C, int K) {
    __shared__ unsigned short lds_a[64 * 64];
    __shared__ unsigned short lds_b[128 * 64];
    int m0 = blockIdx.x * 64, n0 = blockIdx.y * 128;
    int tid = threadIdx.x, wv = tid >> 6, lane = tid & 63;
    f32x4 acc[4][2] = {};
    for (int kt = 0; kt < K; kt += 64) {
        #pragma unroll
        for (int t = 0; t < 2; t++) {
            int slot = t * 256 + tid;
            int row = slot >> 3, cp = slot & 7;
            int cc = cp ^ (row & 7);  // swizzled global source, linear LDS dest
            const unsigned short* ga = A + (size_t)(m0 + row) * K + kt + cc * 8;
            __builtin_amdgcn_global_load_lds((const __attribute__((address_space(1))) void*)ga,
                (__attribute__((address_space(3))) void*)(lds_a + (size_t)(t * 256 + wv * 64) * 8), 16, 0, 0);
        }
        #pragma unroll
        for (int t = 0; t < 4; t++) {
            int slot = t * 256 + tid;
            int row = slot >> 3, cp = slot & 7;
            int cc = cp ^ (row & 7);
            const unsigned short* gb = B + (size_t)(n0 + row) * K + kt + cc * 8;
            __builtin_amdgcn_global_load_lds((const __attribute__((address_space(1))) void*)gb,
                (__attribute__((address_space(3))) void*)(lds_b + (size_t)(t * 256 + wv * 64) * 8), 16, 0, 0);
        }
        __syncthreads();
        #pragma unroll
        for (int kk = 0; kk < 2; kk++) {
            bf16x8 af[4], bg[2];
            #pragma unroll
            for (int m = 0; m < 4; m++) {
                int row = m * 16 + (lane & 15);
                int c = kk * 4 + (lane >> 4);
                int cp = c ^ (row & 7);
                af[m] = *(const bf16x8*)(lds_a + (row * 8 + cp) * 8);
            }
            #pragma unroll
            for (int nn = 0; nn < 2; nn++) {
                int row = wv * 32 + nn * 16 + (lane & 15);
                int c = kk * 4 + (lane >> 4);
                int cp = c ^ (row & 7);
                bg[nn] = *(const bf16x8*)(lds_b + (row * 8 + cp) * 8);
            }
            #pragma unroll
            for (int m = 0; m < 4; m++)
                #pragma unroll
                for (int nn = 0; nn < 2; nn++)
                    acc[m][nn] = __builtin_amdgcn_mfma_f32_16x16x32_bf16(af[m], bg[nn], acc[m][nn], 0, 0, 0);
        }
        __syncthreads();
    }
    // C/D layout: col = lane&15, row = (lane>>4)*4 + reg
    #pragma unroll
    for (int m = 0; m < 4; m++) {
        #pragma unroll
        for (int nn = 0; nn < 2; nn++) {
            int c = n0 + wv * 32 + nn * 16 + (lane & 15);
            #pragma unroll
            for (int j = 0; j < 4; j++) {
                int r = m0 + m * 16 + (lane >> 4) * 4 + j;
                C[(size_t)r * 1024 + c] = f2bf(acc[m][nn][j]);
            }
        }
    }
}

// ---------------- s/d vectors from bf16 xh ----------
__global__ __launch_bounds__(256) void sd_k(const unsigned short* __restrict__ xh,
                                            const float* __restrict__ asrc, const float* __restrict__ adst,
                                            float* __restrict__ s, float* __restrict__ d) {
    int n = blockIdx.x;
    int tid = threadIdx.x, h = tid >> 6, lane = tid & 63;
    ushort4v u = *(const ushort4v*)(xh + (size_t)n * 1024 + h * 256 + lane * 4);
    float4 va = *(const float4*)(asrc + h * 256 + lane * 4);
    float4 vd = *(const float4*)(adst + h * 256 + lane * 4);
    float x0 = bf2f(u[0]), x1 = bf2f(u[1]), x2 = bf2f(u[2]), x3 = bf2f(u[3]);
    float ps = x0 * va.x + x1 * va.y + x2 * va.z + x3 * va.w;
    float pd = x0 * vd.x + x1 * vd.y + x2 * vd.z + x3 * vd.w;
    ps = wred_sum(ps);
    pd = wred_sum(pd);
    if (lane == 0) { s[n * 4 + h] = ps; d[n * 4 + h] = pd; }
}

// ---------------- attention + aggregation: TWO WAVES PER NODE, prefetched edge metadata ----------
__global__ __launch_bounds__(256) void aggr_k(const unsigned short* __restrict__ xh,
                                              const float* __restrict__ svec, const float* __restrict__ dvec,
                                              const int* __restrict__ indptr, const int* __restrict__ srcs,
                                              const float* __restrict__ bias, float* __restrict__ out) {
    __shared__ float ob[2][16][64];     // [nid][acc j][lane] - lane-major, conflict-free
    __shared__ float lpart[2][4];
    __shared__ int   stab[4][64];
    __shared__ float wtab[4][64][4];
    int tid = threadIdx.x, wave = tid >> 6, lane = tid & 63;
    int nid = wave >> 1, parity = wave & 1;
    int n = blockIdx.x * 2 + nid;
    int head = lane >> 4;
    int start = indptr[n], end = indptr[n + 1];
    int cnt = end - start;
    float4 dv4 = ((const float4*)dvec)[n];
    const ushort8v* xb = (const ushort8v*)xh;   // row = 128 ushort8v
    size_t loff = (size_t)(lane << 1);
    float acc[16];
    #pragma unroll
    for (int j = 0; j < 16; j++) acc[j] = 0.f;
    float ls0 = 0.f, ls1 = 0.f, ls2 = 0.f, ls3 = 0.f;
    int nw = (cnt > parity) ? ((cnt - parity + 1) >> 1) : 0;   // this wave's edge count
    for (int c0 = 0; c0 < nw; c0 += 64) {
        int m = min(64, nw - c0);
        if (lane < m) {
            int j = c0 + lane;
            int sv = srcs[start + parity + 2 * j];
            float4 s4 = ((const float4*)svec)[sv];
            float e0 = s4.x + dv4.x, e1 = s4.y + dv4.y, e2 = s4.z + dv4.z, e3 = s4.w + dv4.w;
            e0 = e0 > 0.f ? e0 : 0.2f * e0; e1 = e1 > 0.f ? e1 : 0.2f * e1;
            e2 = e2 > 0.f ? e2 : 0.2f * e2; e3 = e3 > 0.f ? e3 : 0.2f * e3;
            float w0 = __expf(e0), w1 = __expf(e1), w2 = __expf(e2), w3 = __expf(e3);
            ls0 += w0; ls1 += w1; ls2 += w2; ls3 += w3;
            stab[wave][lane] = sv;
            float4 wv = {w0, w1, w2, w3};
            *(float4*)&wtab[wave][lane][0] = wv;
        }
        // same-wave LDS write->read: ordered by lgkmcnt, no barrier needed
        int k = 0;
        for (; k + 4 <= m; k += 4) {
            int s0 = stab[wave][k], s1 = stab[wave][k + 1];
            int s2 = stab[wave][k + 2], s3 = stab[wave][k + 3];
            float w0 = wtab[wave][k][head],     w1 = wtab[wave][k + 1][head];
            float w2 = wtab[wave][k + 2][head], w3 = wtab[wave][k + 3][head];
            ushort8v a0 = xb[(size_t)s0 * 128 + loff], a1 = xb[(size_t)s0 * 128 + loff + 1];
            ushort8v b0 = xb[(size_t)s1 * 128 + loff], b1 = xb[(size_t)s1 * 128 + loff + 1];
            ushort8v c0v = xb[(size_t)s2 * 128 + loff], c1v = xb[(size_t)s2 * 128 + loff + 1];
            ushort8v d0 = xb[(size_t)s3 * 128 + loff], d1 = xb[(size_t)s3 * 128 + loff + 1];
            #pragma unroll
            for (int j = 0; j < 8; j++) {
                acc[j]     += w0 * bf2f(a0[j]) + w1 * bf2f(b0[j]) + w2 * bf2f(c0v[j]) + w3 * bf2f(d0[j]);
                acc[8 + j] += w0 * bf2f(a1[j]) + w1 * bf2f(b1[j]) + w2 * bf2f(c1v[j]) + w3 * bf2f(d1[j]);
            }
        }
        for (; k < m; k++) {
            int s0 = stab[wave][k];
            float w0 = wtab[wave][k][head];
            ushort8v a0 = xb[(size_t)s0 * 128 + loff], a1 = xb[(size_t)s0 * 128 + loff + 1];
            #pragma unroll
            for (int j = 0; j < 8; j++) {
                acc[j]     += w0 * bf2f(a0[j]);
                acc[8 + j] += w0 * bf2f(a1[j]);
            }
        }
    }
    ls0 = wred_sum(ls0); ls1 = wred_sum(ls1); ls2 = wred_sum(ls2); ls3 = wred_sum(ls3);
    if (parity == 1) {
        #pragma unroll
        for (int j = 0; j < 16; j++) ob[nid][j][lane] = acc[j];
        if (lane == 0) {
            lpart[nid][0] = ls0; lpart[nid][1] = ls1;
            lpart[nid][2] = ls2; lpart[nid][3] = ls3;
        }
    }
    __syncthreads();
    if (parity == 0) {
        #pragma unroll
        for (int j = 0; j < 16; j++) acc[j] += ob[nid][j][lane];
        float Lown = head < 2 ? (head == 0 ? ls0 : ls1) : (head == 2 ? ls2 : ls3);
        float L = Lown + lpart[nid][head];
        float inv = 0.25f / L;   // fold head-mean
        #pragma unroll
        for (int j = 0; j < 16; j++) {
            float r = acc[j] * inv;
            r += __shfl_xor(r, 16, 64);
            r += __shfl_xor(r, 32, 64);
            acc[j] = r;
        }
        if (lane < 16) {
            int c0 = lane << 4;
            const float4* bp = (const float4*)(bias + c0);
            float* op = out + (size_t)n * 256 + c0;
            #pragma unroll
            for (int q = 0; q < 4; q++) {
                float4 bv = bp[q];
                float4 ov;
                ov.x = acc[q * 4 + 0] + bv.x;
                ov.y = acc[q * 4 + 1] + bv.y;
                ov.z = acc[q * 4 + 2] + bv.z;
                ov.w = acc[q * 4 + 3] + bv.w;
                *(float4*)(op + q * 4) = ov;
            }
        }
    }
}

// ---------------- BN stats / apply ----------
__global__ __launch_bounds__(256) void bnstat_k(const float* __restrict__ h, float* __restrict__ bnsum,
                                                float* __restrict__ bnss, int n, int rpb) {
    int c = threadIdx.x;
    int r0 = blockIdx.x * rpb;
    int r1 = min(r0 + rpb, n);
    float s = 0.f, q = 0.f;
    for (int r = r0; r < r1; r++) {
        float v = h[(size_t)r * 256 + c];
        s += v; q += v * v;
    }
    atomicAdd(&bnsum[c], s);
    atomicAdd(&bnss[c], q);
}

__global__ __launch_bounds__(256) void bnapply_k(const float* __restrict__ h, const float* __restrict__ bnsum,
                                                 const float* __restrict__ bnss, const float* __restrict__ gamma,
                                                 const float* __restrict__ beta, unsigned short* __restrict__ o,
                                                 int nrows, float invn) {
    int row = blockIdx.x, c = threadIdx.x;
    unsigned short r;
    if (row < nrows) {
        float mu = bnsum[c] * invn;
        float var = bnss[c] * invn - mu * mu;
        float v = (h[(size_t)row * 256 + c] - mu) * rsqrtf(var + 1e-5f) * gamma[c] + beta[c];
        v = fmaxf(v, 0.f);
        r = f2bf(v);
    } else {
        r = 0;
    }
    o[(size_t)row * 256 + c] = r;
}

extern "C" void kernel_launch(void* const* d_in, const int* in_sizes, int n_in,
                              void* d_out, int out_size, void* d_ws, size_t ws_size,
                              hipStream_t stream) {
    const float* x     = (const float*)d_in[0];
    const int*   ei    = (const int*)d_in[1];
    const float* W1    = (const float*)d_in[2];
    const float* as1   = (const float*)d_in[3];
    const float* ad1   = (const float*)d_in[4];
    const float* b1    = (const float*)d_in[5];
    const float* gamma = (const float*)d_in[6];
    const float* beta  = (const float*)d_in[7];
    const float* W2    = (const float*)d_in[8];
    const float* as2   = (const float*)d_in[9];
    const float* ad2   = (const float*)d_in[10];
    const float* b2    = (const float*)d_in[11];
    float* out = (float*)d_out;

    const int N = in_sizes[0] / 768;     // 10000 (multiple of 2)
    const int E = in_sizes[1] / 2;       // 160000
    const int Et = E + N;                // edges + self loops
    const int Mpad = ((N + 63) / 64) * 64;     // 10048 (64-aligned for 64-row GEMM tiles)

    char* w = (char*)d_ws;
    size_t o = 0;
    auto alloc = [&](size_t b) { size_t r = o; o += (b + 255) & ~(size_t)255; return r; };
    unsigned short* xh     = (unsigned short*)(w + alloc((size_t)Mpad * 1024 * 2));
    unsigned short* xbf    = (unsigned short*)(w + alloc((size_t)Mpad * 768 * 2));
    unsigned short* hbf    = (unsigned short*)(w + alloc((size_t)Mpad * 256 * 2));
    unsigned short* w1t    = (unsigned short*)(w + alloc((size_t)1024 * 768 * 2));
    unsigned short* w2t    = (unsigned short*)(w + alloc((size_t)1024 * 256 * 2));
    float*          svec   = (float*)(w + alloc((size_t)N * 4 * 4));
    float*          dvec   = (float*)(w + alloc((size_t)N * 4 * 4));
    float*          hbuf   = (float*)(w + alloc((size_t)N * 256 * 4));
    int*            indptr = (int*)(w + alloc((size_t)(N + 1) * 4));
    int*            cursor = (int*)(w + alloc((size_t)N * 4));
    int*            count  = (int*)(w + alloc((size_t)N * 4));
    int*            bsum   = (int*)(w + alloc(256));
    float*          bnsum  = (float*)(w + alloc(256 * 4));   // bnss directly after: one memset covers both
    float*          bnss   = (float*)(w + alloc(256 * 4));
    int*            srcs   = (int*)(w + alloc((size_t)Et * 4));

    hipMemsetAsync(count, 0, (size_t)N * 4, stream);
    hipMemsetAsync(bnsum, 0, 2048, stream);  // bnsum + bnss (contiguous, 256-aligned)

    // fused prep: cvtpad | tr(W1) | tr(W2) | hist
    int nbA = (Mpad * 96) / 256;         // 3768
    int nbB = (768 / 32) * (1024 / 32);  // 768
    int nbC = (256 / 32) * (1024 / 32);  // 256
    int nbD = (Et + 255) / 256;          // 665
    prep_k<<<nbA + nbB + nbC + nbD, 256, 0, stream>>>(x, xbf, W1, w1t, W2, w2t, ei, count,
                                                      N, E, Et, nbA, nbB, nbC);
    int nbS = (N + 255) / 256;           // 40
    scanA_k<<<nbS, 256, 0, stream>>>(count, indptr, bsum, N);
    scanC_k<<<nbS, 256, 0, stream>>>(indptr, cursor, bsum, N, Et, nbS);
    scatter_k<<<(Et + 255) / 256, 256, 0, stream>>>(ei, cursor, srcs, E, Et);

    // layer 1
    gemm_k<<<dim3(Mpad / 64, 8), 256, 0, stream>>>(xbf, w1t, xh, 768);
    sd_k<<<N, 256, 0, stream>>>(xh, as1, ad1, svec, dvec);
    aggr_k<<<N / 2, 256, 0, stream>>>(xh, svec, dvec, indptr, srcs, b1, hbuf);

    // BN + ReLU -> bf16 padded
    bnstat_k<<<320, 256, 0, stream>>>(hbuf, bnsum, bnss, N, (N + 319) / 320);
    bnapply_k<<<Mpad, 256, 0, stream>>>(hbuf, bnsum, bnss, gamma, beta, hbf, N, 1.0f / (float)N);

    // layer 2
    gemm_k<<<dim3(Mpad / 64, 8), 256, 0, stream>>>(hbf, w2t, xh, 256);
    sd_k<<<N, 256, 0, stream>>>(xh, as2, ad2, svec, dvec);
    aggr_k<<<N / 2, 256, 0, stream>>>(xh, svec, dvec, indptr, srcs, b2, out);
}